// Round 1
// baseline (8159.455 us; speedup 1.0000x reference)
//
#include <hip/hip_runtime.h>
#include <hip/hip_bf16.h>
#include <math.h>

// Problem constants
// B=8, N=1024, F=64, HEADS=8, u1=128, u2=64

#define NB 8
#define NN 1024
#define NF 64
#define NH 8

// ---------------------------------------------------------------------------
// Kernel A: fused QKV projection.
// In: [B*N, KIN] row-major. Weights: [KIN, HD] row-major (HD = NH*D).
// Out: Q [B,H,N,D], KT [B,H,D,N] (transposed for coalesced score pass),
//      V [B,H,N,D].
// One block per input row.
// ---------------------------------------------------------------------------
template <int KIN, int HD, int D>
__global__ void proj_qkv(const float* __restrict__ X,
                         const float* __restrict__ Wq,
                         const float* __restrict__ Wk,
                         const float* __restrict__ Wv,
                         float* __restrict__ Q,
                         float* __restrict__ KT,
                         float* __restrict__ V) {
    const int r = blockIdx.x;          // 0 .. B*N-1
    const int b = r >> 10;             // N = 1024
    const int n = r & 1023;

    __shared__ float xin[KIN];
    for (int f = threadIdx.x; f < KIN; f += blockDim.x) xin[f] = X[(size_t)r * KIN + f];
    __syncthreads();

    for (int c = threadIdx.x; c < HD; c += blockDim.x) {
        float aq = 0.f, ak = 0.f, av = 0.f;
#pragma unroll 8
        for (int f = 0; f < KIN; ++f) {
            const float x = xin[f];
            aq = fmaf(x, Wq[(size_t)f * HD + c], aq);
            ak = fmaf(x, Wk[(size_t)f * HD + c], ak);
            av = fmaf(x, Wv[(size_t)f * HD + c], av);
        }
        const int h = c / D;
        const int d = c % D;
        const int bh = b * NH + h;
        Q[((size_t)bh * NN + n) * D + d]  = aq;
        KT[((size_t)bh * D + d) * NN + n] = ak;
        V[((size_t)bh * NN + n) * D + d]  = av;
    }
}

// ---------------------------------------------------------------------------
// Kernel B: masked softmax attention, one block (256 thr) per (b, h, q-row).
// scores[m] = (q . K[m]) * scale - 1e9 * A[b, n, m];  w = softmax(scores)
// ctx[d] = sum_m w[m] * V[m, d]
// ---------------------------------------------------------------------------
template <int D>
__global__ void attn_row(const float* __restrict__ Q,
                         const float* __restrict__ KT,
                         const float* __restrict__ V,
                         const float* __restrict__ A,
                         const float scale,
                         float* __restrict__ ctx) {
    const int bid = blockIdx.x;        // B*H*N blocks
    const int n   = bid & 1023;
    const int bh  = bid >> 10;         // 0..63
    const int b   = bh >> 3;

    const float* __restrict__ qp = Q + ((size_t)bh * NN + n) * D;
    const float* __restrict__ kp = KT + (size_t)bh * D * NN;
    const float* __restrict__ vp = V + (size_t)bh * NN * D;
    const float* __restrict__ ap = A + (size_t)b * NN * NN + (size_t)n * NN;

    __shared__ float sq[D];
    __shared__ float ss[NN];
    __shared__ float red[8];

    const int tid = threadIdx.x;       // 256 threads
    for (int d = tid; d < D; d += 256) sq[d] = qp[d];
    __syncthreads();

    // pass 1: scores (kept in registers), local max
    float sv[4];
    float lmax = -3.0e38f;
#pragma unroll
    for (int mi = 0; mi < 4; ++mi) {
        const int m = tid + mi * 256;
        float acc = 0.f;
#pragma unroll 8
        for (int d = 0; d < D; ++d) acc = fmaf(sq[d], kp[(size_t)d * NN + m], acc);
        const float s = acc * scale - 1.0e9f * ap[m];
        sv[mi] = s;
        lmax = fmaxf(lmax, s);
    }
    // block max reduce (wave64 shuffle + LDS)
#pragma unroll
    for (int off = 32; off; off >>= 1) lmax = fmaxf(lmax, __shfl_down(lmax, off));
    if ((tid & 63) == 0) red[tid >> 6] = lmax;
    __syncthreads();
    const float bmax = fmaxf(fmaxf(red[0], red[1]), fmaxf(red[2], red[3]));

    // pass 2: exp + sum
    float lsum = 0.f;
#pragma unroll
    for (int mi = 0; mi < 4; ++mi) {
        const float e = __expf(sv[mi] - bmax);
        ss[tid + mi * 256] = e;
        lsum += e;
    }
#pragma unroll
    for (int off = 32; off; off >>= 1) lsum += __shfl_down(lsum, off);
    if ((tid & 63) == 0) red[4 + (tid >> 6)] = lsum;
    __syncthreads();
    const float inv = 1.0f / (red[4] + red[5] + red[6] + red[7]);

    // pass 3: ctx[d] = sum_m w[m] V[m,d]
    constexpr int G = 256 / D;         // 2 (D=128) or 4 (D=64)
    const int d = tid % D;
    const int g = tid / D;
    float acc = 0.f;
    for (int m = g; m < NN; m += G) acc = fmaf(ss[m], vp[(size_t)m * D + d], acc);
    __syncthreads();                   // all reads of ss done
    ss[g * D + d] = acc;
    __syncthreads();
    if (g == 0) {
        float tot = 0.f;
#pragma unroll
        for (int gg = 0; gg < G; ++gg) tot += ss[gg * D + d];
        ctx[((size_t)bh * NN + n) * D + d] = tot * inv;
    }
}

// ---------------------------------------------------------------------------
// Kernel C: output projection.  ctx [B,H,N,D] -> gather row [NH*D] -> @ Wo
// Wo: [NH*D, COUT].  One block (COUT threads) per row.
// ---------------------------------------------------------------------------
template <int D, int COUT>
__global__ void wo_proj(const float* __restrict__ ctx,
                        const float* __restrict__ Wo,
                        float* __restrict__ Hout) {
    constexpr int CIN = NH * D;
    const int r = blockIdx.x;
    const int b = r >> 10;
    const int n = r & 1023;

    __shared__ float cr[CIN];
    for (int c = threadIdx.x; c < CIN; c += blockDim.x) {
        const int h = c / D;
        const int d = c % D;
        cr[c] = ctx[(((size_t)(b * NH + h)) * NN + n) * D + d];
    }
    __syncthreads();

    const int o = threadIdx.x;
    if (o < COUT) {
        float acc = 0.f;
#pragma unroll 8
        for (int c = 0; c < CIN; ++c) acc = fmaf(cr[c], Wo[(size_t)c * COUT + o], acc);
        Hout[(size_t)r * COUT + o] = acc;
    }
}

// ---------------------------------------------------------------------------
// Kernel D: mean over N, then 3-layer MLP.  One block per batch element.
// H2: [B, N, 64].  W1 [64,32] b1[32], W2 [32,16] b2[16], W3 [16,1] b3[1].
// ---------------------------------------------------------------------------
__global__ void pool_mlp(const float* __restrict__ H2,
                         const float* __restrict__ W1, const float* __restrict__ b1,
                         const float* __restrict__ W2, const float* __restrict__ b2,
                         const float* __restrict__ W3, const float* __restrict__ b3,
                         float* __restrict__ out) {
    const int b = blockIdx.x;
    const int tid = threadIdx.x;       // 256
    __shared__ float red[4][64];
    __shared__ float mean[64];
    __shared__ float h1[32];
    __shared__ float h2[16];

    const int o = tid & 63;
    const int g = tid >> 6;
    float acc = 0.f;
    for (int n = g; n < NN; n += 4) acc += H2[((size_t)b * NN + n) * 64 + o];
    red[g][o] = acc;
    __syncthreads();
    if (g == 0) mean[o] = (red[0][o] + red[1][o] + red[2][o] + red[3][o]) * (1.0f / 1024.0f);
    __syncthreads();

    if (tid < 32) {
        float a = b1[tid];
#pragma unroll
        for (int f = 0; f < 64; ++f) a = fmaf(mean[f], W1[f * 32 + tid], a);
        h1[tid] = fmaxf(a, 0.f);
    }
    __syncthreads();
    if (tid < 16) {
        float a = b2[tid];
#pragma unroll
        for (int f = 0; f < 32; ++f) a = fmaf(h1[f], W2[f * 16 + tid], a);
        h2[tid] = fmaxf(a, 0.f);
    }
    __syncthreads();
    if (tid == 0) {
        float a = b3[0];
#pragma unroll
        for (int f = 0; f < 16; ++f) a = fmaf(h2[f], W3[f], a);
        out[b] = a;
    }
}

// ---------------------------------------------------------------------------
extern "C" void kernel_launch(void* const* d_in, const int* in_sizes, int n_in,
                              void* d_out, int out_size, void* d_ws, size_t ws_size,
                              hipStream_t stream) {
    const float* X   = (const float*)d_in[0];
    const float* A   = (const float*)d_in[1];
    const float* Wq1 = (const float*)d_in[2];
    const float* Wk1 = (const float*)d_in[3];
    const float* Wv1 = (const float*)d_in[4];
    const float* Wo1 = (const float*)d_in[5];
    const float* Wq2 = (const float*)d_in[6];
    const float* Wk2 = (const float*)d_in[7];
    const float* Wv2 = (const float*)d_in[8];
    const float* Wo2 = (const float*)d_in[9];
    const float* W1  = (const float*)d_in[10];
    const float* b1  = (const float*)d_in[11];
    const float* W2  = (const float*)d_in[12];
    const float* b2  = (const float*)d_in[13];
    const float* W3  = (const float*)d_in[14];
    const float* b3  = (const float*)d_in[15];
    float* out = (float*)d_out;

    // workspace layout (floats)
    float* ws = (float*)d_ws;
    const size_t M1 = (size_t)1024 * 1024;
    float* Q1   = ws;                  //  8M floats  [B,H,N,128]
    float* KT1  = ws + 8 * M1;         //  8M         [B,H,128,N]
    float* V1   = ws + 16 * M1;        //  8M         [B,H,N,128]
    float* ctx1 = ws + 24 * M1;        //  8M         [B,H,N,128]
    float* H1   = ws + 32 * M1;        //  1M         [B,N,128]
    float* H2   = ws + 33 * M1;        //  0.5M       [B,N,64]
    // layer-2 QKV overlays layer-1 QKV region (dead by then)
    float* Q2   = ws;                  //  4M  [B,H,N,64]
    float* KT2  = ws + 4 * M1;         //  4M  [B,H,64,N]
    float* V2   = ws + 8 * M1;         //  4M  [B,H,N,64]
    float* ctx2 = ctx1;                //  4M  [B,H,N,64]

    const int ROWS = NB * NN;          // 8192
    const int BHN  = NB * NH * NN;     // 65536

    // ----- layer 1 (units = 128) -----
    proj_qkv<64, 1024, 128><<<ROWS, 256, 0, stream>>>(X, Wq1, Wk1, Wv1, Q1, KT1, V1);
    attn_row<128><<<BHN, 256, 0, stream>>>(Q1, KT1, V1, A, 0.08838834764831845f, ctx1);
    wo_proj<128, 128><<<ROWS, 128, 0, stream>>>(ctx1, Wo1, H1);

    // ----- layer 2 (units = 64) -----
    proj_qkv<128, 512, 64><<<ROWS, 256, 0, stream>>>(H1, Wq2, Wk2, Wv2, Q2, KT2, V2);
    attn_row<64><<<BHN, 256, 0, stream>>>(Q2, KT2, V2, A, 0.125f, ctx2);
    wo_proj<64, 64><<<ROWS, 64, 0, stream>>>(ctx2, Wo2, H2);

    // ----- pool + MLP -----
    pool_mlp<<<NB, 256, 0, stream>>>(H2, W1, b1, W2, b2, W3, b3, out);
}

// Round 2
// 1829.329 us; speedup vs baseline: 4.4604x; 4.4604x over previous
//
#include <hip/hip_runtime.h>
#include <hip/hip_bf16.h>
#include <math.h>

// B=8, N=1024, F=64, HEADS=8, u1=128, u2=64
#define NB 8
#define NN 1024
#define NF 64
#define NH 8

// ---------------------------------------------------------------------------
// Kernel A: row-tiled fused QKV projection.
// X: [B*N, KIN] row-major. W*: [KIN, HD]. Out Q,K,V: [B,H,N,D].
// RB=16 rows per block, 256 threads, CPT = HD/256 columns per thread.
// ---------------------------------------------------------------------------
template <int KIN, int HD, int D>
__global__ __launch_bounds__(256)
void proj_qkv_t(const float* __restrict__ X,
                const float* __restrict__ Wq,
                const float* __restrict__ Wk,
                const float* __restrict__ Wv,
                float* __restrict__ Q,
                float* __restrict__ K,
                float* __restrict__ V) {
    constexpr int RB  = 16;
    constexpr int CPT = HD / 256;
    const int r0 = blockIdx.x * RB;
    const int b  = r0 >> 10;
    const int n0 = r0 & 1023;
    const int tid = threadIdx.x;

    __shared__ float xs[RB][KIN];
    for (int i = tid; i < RB * KIN / 4; i += 256) {
        const int rr = i / (KIN / 4), ff = (i % (KIN / 4)) * 4;
        *(float4*)&xs[rr][ff] = *(const float4*)&X[(size_t)(r0 + rr) * KIN + ff];
    }
    __syncthreads();

    const float* Ws[3] = {Wq, Wk, Wv};
    float*       Os[3] = {Q, K, V};
#pragma unroll 1
    for (int w = 0; w < 3; ++w) {
        const float* __restrict__ W = Ws[w];
        float acc[RB][CPT];
#pragma unroll
        for (int rr = 0; rr < RB; ++rr)
#pragma unroll
            for (int k = 0; k < CPT; ++k) acc[rr][k] = 0.f;

#pragma unroll 4
        for (int f = 0; f < KIN; ++f) {
            float wv[CPT];
#pragma unroll
            for (int k = 0; k < CPT; ++k) wv[k] = W[(size_t)f * HD + tid + 256 * k];
#pragma unroll
            for (int rr = 0; rr < RB; ++rr) {
                const float xv = xs[rr][f];
#pragma unroll
                for (int k = 0; k < CPT; ++k) acc[rr][k] = fmaf(xv, wv[k], acc[rr][k]);
            }
        }
        float* __restrict__ O = Os[w];
#pragma unroll
        for (int k = 0; k < CPT; ++k) {
            const int c = tid + 256 * k;
            const int h = c / D, d = c % D;
#pragma unroll
            for (int rr = 0; rr < RB; ++rr)
                O[((size_t)(b * NH + h) * NN + (n0 + rr)) * D + d] = acc[rr][k];
        }
    }
}

// ---------------------------------------------------------------------------
// Kernel B: flash-style masked attention, fp32, online softmax.
// One block = (b, h, 16 q-rows). Chunks of MB=32 keys staged in LDS.
// Q,K,V: [B,H,N,D].  A: [B,N,N].  O: [B,N,H,D] (head-interleaved rows).
// ---------------------------------------------------------------------------
template <int D>
__global__ __launch_bounds__(256)
void attn_flash(const float* __restrict__ Q,
                const float* __restrict__ K,
                const float* __restrict__ V,
                const float* __restrict__ A,
                const float scale,
                float* __restrict__ O) {
    constexpr int QB = 16;
    constexpr int MB = 32;
    constexpr int DP = D + 4;          // pad: stride 132/68 -> 2-way bank alias (free)
    constexpr int CG  = D / 4;         // float4 col groups (32 or 16)
    constexpr int RG  = 256 / CG;      // row groups (8 or 16)
    constexpr int QPT = QB / RG;       // q per thread in ctx phase (2 or 1)

    const int bid = blockIdx.x;
    const int qt  = bid & (NN / QB - 1);      // 64 q-tiles
    const int bh  = bid / (NN / QB);
    const int h   = bh & 7, b = bh >> 3;
    const int q0  = qt * QB;
    const int tid = threadIdx.x;

    __shared__ float Qs[QB][DP];
    __shared__ float Ks[MB][DP];
    __shared__ float Vs[MB][DP];
    __shared__ float Ps[QB][MB];
    __shared__ float Ms[QB], Ls[QB], Al[QB];

    // stage Q tile
    const float* __restrict__ qg = Q + ((size_t)bh * NN + q0) * D;
    for (int i = tid; i < QB * D / 4; i += 256) {
        const int q = i / (D / 4), dd = (i % (D / 4)) * 4;
        *(float4*)&Qs[q][dd] = *(const float4*)&qg[(size_t)q * D + dd];
    }
    if (tid < QB) { Ms[tid] = -3.0e38f; Ls[tid] = 0.f; }

    // score-phase mapping: q = tid>>4, m = (tid&15) + 16j
    const int sq = tid >> 4;
    const int mt = tid & 15;
    const float* __restrict__ arow = A + ((size_t)b * NN + (q0 + sq)) * NN;

    // ctx-phase mapping: rg = tid/CG -> q = rg*QPT..; c = tid%CG -> d = 4c
    const int rg = tid / CG;
    const int cc = tid % CG;
    float acc[QPT][4];
#pragma unroll
    for (int qi = 0; qi < QPT; ++qi)
#pragma unroll
        for (int j = 0; j < 4; ++j) acc[qi][j] = 0.f;

    const float* __restrict__ kg = K + (size_t)bh * NN * D;
    const float* __restrict__ vg = V + (size_t)bh * NN * D;

    for (int ch = 0; ch < NN / MB; ++ch) {
        // ---- stage K,V chunk ----
        const size_t base = (size_t)(ch * MB) * D;
        for (int i = tid; i < MB * D / 4; i += 256) {
            const int m = i / (D / 4), dd = (i % (D / 4)) * 4;
            *(float4*)&Ks[m][dd] = *(const float4*)&kg[base + (size_t)m * D + dd];
            *(float4*)&Vs[m][dd] = *(const float4*)&vg[base + (size_t)m * D + dd];
        }
        __syncthreads();

        // ---- scores: 2 per thread ----
        float s[2];
#pragma unroll
        for (int j = 0; j < 2; ++j) {
            const int m = mt + 16 * j;
            float d0 = 0.f, d1 = 0.f, d2 = 0.f, d3 = 0.f;
#pragma unroll
            for (int dd = 0; dd < D; dd += 4) {
                const float4 kk = *(const float4*)&Ks[m][dd];
                const float4 qq = *(const float4*)&Qs[sq][dd];
                d0 = fmaf(qq.x, kk.x, d0);
                d1 = fmaf(qq.y, kk.y, d1);
                d2 = fmaf(qq.z, kk.z, d2);
                d3 = fmaf(qq.w, kk.w, d3);
            }
            const float dot = (d0 + d1) + (d2 + d3);
            s[j] = dot * scale - 1.0e9f * arow[ch * MB + m];
        }
        // per-q chunk max (16-lane groups)
        float cmax = fmaxf(s[0], s[1]);
#pragma unroll
        for (int off = 1; off < 16; off <<= 1)
            cmax = fmaxf(cmax, __shfl_xor(cmax, off, 16));
        const float Mold = Ms[sq];
        const float newM = fmaxf(Mold, cmax);
        const float p0 = __expf(s[0] - newM);
        const float p1 = __expf(s[1] - newM);
        float csum = p0 + p1;
#pragma unroll
        for (int off = 1; off < 16; off <<= 1)
            csum += __shfl_xor(csum, off, 16);
        Ps[sq][mt]      = p0;
        Ps[sq][mt + 16] = p1;
        if (mt == 0) {
            const float alpha = __expf(Mold - newM);
            Ms[sq] = newM;
            Al[sq] = alpha;
            Ls[sq] = Ls[sq] * alpha + csum;
        }
        __syncthreads();   // Ps, Al visible

        // ---- ctx update ----
#pragma unroll
        for (int qi = 0; qi < QPT; ++qi) {
            const float alpha = Al[rg * QPT + qi];
#pragma unroll
            for (int j = 0; j < 4; ++j) acc[qi][j] *= alpha;
        }
#pragma unroll 2
        for (int m = 0; m < MB; ++m) {
            const float4 vv = *(const float4*)&Vs[m][4 * cc];
#pragma unroll
            for (int qi = 0; qi < QPT; ++qi) {
                const float pp = Ps[rg * QPT + qi][m];
                acc[qi][0] = fmaf(pp, vv.x, acc[qi][0]);
                acc[qi][1] = fmaf(pp, vv.y, acc[qi][1]);
                acc[qi][2] = fmaf(pp, vv.z, acc[qi][2]);
                acc[qi][3] = fmaf(pp, vv.w, acc[qi][3]);
            }
        }
        __syncthreads();   // done reading Ks/Vs/Ps
    }

    // ---- normalize + write: O[b][n][h][d] ----
#pragma unroll
    for (int qi = 0; qi < QPT; ++qi) {
        const int q = rg * QPT + qi;
        const float inv = 1.0f / Ls[q];
        float4 o;
        o.x = acc[qi][0] * inv; o.y = acc[qi][1] * inv;
        o.z = acc[qi][2] * inv; o.w = acc[qi][3] * inv;
        *(float4*)&O[(((size_t)b * NN + (q0 + q)) * NH + h) * D + 4 * cc] = o;
    }
}

// ---------------------------------------------------------------------------
// Kernel C: row-tiled output projection. Hin: [rows, CIN] (contiguous),
// Wo: [CIN, COUT], Hout: [rows, COUT].
// ---------------------------------------------------------------------------
template <int CIN, int COUT, int RB>
__global__ __launch_bounds__(256)
void wo_proj_t(const float* __restrict__ Hin,
               const float* __restrict__ Wo,
               float* __restrict__ Hout) {
    constexpr int G   = 256 / COUT;
    constexpr int RPT = RB / G;
    const int r0  = blockIdx.x * RB;
    const int tid = threadIdx.x;

    __shared__ float xs[RB][CIN];
    for (int i = tid; i < RB * CIN / 4; i += 256) {
        const int rr = i / (CIN / 4), ff = (i % (CIN / 4)) * 4;
        *(float4*)&xs[rr][ff] = *(const float4*)&Hin[(size_t)(r0 + rr) * CIN + ff];
    }
    __syncthreads();

    const int c = tid % COUT;
    const int g = tid / COUT;
    float acc[RPT];
#pragma unroll
    for (int j = 0; j < RPT; ++j) acc[j] = 0.f;

#pragma unroll 4
    for (int f = 0; f < CIN; ++f) {
        const float wv = Wo[(size_t)f * COUT + c];
#pragma unroll
        for (int j = 0; j < RPT; ++j)
            acc[j] = fmaf(xs[g * RPT + j][f], wv, acc[j]);
    }
#pragma unroll
    for (int j = 0; j < RPT; ++j)
        Hout[(size_t)(r0 + g * RPT + j) * COUT + c] = acc[j];
}

// ---------------------------------------------------------------------------
// Kernel D: mean over N + 3-layer MLP. One block per batch element.
// ---------------------------------------------------------------------------
__global__ void pool_mlp(const float* __restrict__ H2,
                         const float* __restrict__ W1, const float* __restrict__ b1,
                         const float* __restrict__ W2, const float* __restrict__ b2,
                         const float* __restrict__ W3, const float* __restrict__ b3,
                         float* __restrict__ out) {
    const int b = blockIdx.x;
    const int tid = threadIdx.x;       // 256
    __shared__ float red[4][64];
    __shared__ float mean[64];
    __shared__ float h1[32];
    __shared__ float h2[16];

    const int o = tid & 63;
    const int g = tid >> 6;
    float acc = 0.f;
    for (int n = g; n < NN; n += 4) acc += H2[((size_t)b * NN + n) * 64 + o];
    red[g][o] = acc;
    __syncthreads();
    if (g == 0) mean[o] = (red[0][o] + red[1][o] + red[2][o] + red[3][o]) * (1.0f / 1024.0f);
    __syncthreads();

    if (tid < 32) {
        float a = b1[tid];
#pragma unroll
        for (int f = 0; f < 64; ++f) a = fmaf(mean[f], W1[f * 32 + tid], a);
        h1[tid] = fmaxf(a, 0.f);
    }
    __syncthreads();
    if (tid < 16) {
        float a = b2[tid];
#pragma unroll
        for (int f = 0; f < 32; ++f) a = fmaf(h1[f], W2[f * 16 + tid], a);
        h2[tid] = fmaxf(a, 0.f);
    }
    __syncthreads();
    if (tid == 0) {
        float a = b3[0];
#pragma unroll
        for (int f = 0; f < 16; ++f) a = fmaf(h2[f], W3[f], a);
        out[b] = a;
    }
}

// ---------------------------------------------------------------------------
extern "C" void kernel_launch(void* const* d_in, const int* in_sizes, int n_in,
                              void* d_out, int out_size, void* d_ws, size_t ws_size,
                              hipStream_t stream) {
    const float* X   = (const float*)d_in[0];
    const float* A   = (const float*)d_in[1];
    const float* Wq1 = (const float*)d_in[2];
    const float* Wk1 = (const float*)d_in[3];
    const float* Wv1 = (const float*)d_in[4];
    const float* Wo1 = (const float*)d_in[5];
    const float* Wq2 = (const float*)d_in[6];
    const float* Wk2 = (const float*)d_in[7];
    const float* Wv2 = (const float*)d_in[8];
    const float* Wo2 = (const float*)d_in[9];
    const float* W1  = (const float*)d_in[10];
    const float* b1  = (const float*)d_in[11];
    const float* W2  = (const float*)d_in[12];
    const float* b2  = (const float*)d_in[13];
    const float* W3  = (const float*)d_in[14];
    const float* b3  = (const float*)d_in[15];
    float* out = (float*)d_out;

    float* ws = (float*)d_ws;
    const size_t M1 = (size_t)1024 * 1024;
    float* Q1   = ws;                  // 8M floats [B,H,N,128]
    float* K1   = ws + 8 * M1;         // 8M
    float* V1   = ws + 16 * M1;        // 8M
    float* ctx1 = ws + 24 * M1;        // 8M [B,N,H*128]
    float* H1   = ws + 32 * M1;        // 1M [B,N,128]
    float* H2   = ws + 33 * M1;        // 0.5M [B,N,64]
    float* Q2   = ws;                  // 4M [B,H,N,64]
    float* K2   = ws + 4 * M1;
    float* V2   = ws + 8 * M1;
    float* ctx2 = ctx1;                // 4M [B,N,H*64]

    const int ROWS = NB * NN;          // 8192

    // ----- layer 1 (D = 128) -----
    proj_qkv_t<64, 1024, 128><<<ROWS / 16, 256, 0, stream>>>(X, Wq1, Wk1, Wv1, Q1, K1, V1);
    attn_flash<128><<<NB * NH * (NN / 16), 256, 0, stream>>>(Q1, K1, V1, A,
                                                             0.08838834764831845f, ctx1);
    wo_proj_t<1024, 128, 8><<<ROWS / 8, 256, 0, stream>>>(ctx1, Wo1, H1);

    // ----- layer 2 (D = 64) -----
    proj_qkv_t<128, 512, 64><<<ROWS / 16, 256, 0, stream>>>(H1, Wq2, Wk2, Wv2, Q2, K2, V2);
    attn_flash<64><<<NB * NH * (NN / 16), 256, 0, stream>>>(Q2, K2, V2, A, 0.125f, ctx2);
    wo_proj_t<512, 64, 16><<<ROWS / 16, 256, 0, stream>>>(ctx2, Wo2, H2);

    // ----- pool + MLP -----
    pool_mlp<<<NB, 256, 0, stream>>>(H2, W1, b1, W2, b2, W3, b3, out);
}

// Round 3
// 512.849 us; speedup vs baseline: 15.9101x; 3.5670x over previous
//
#include <hip/hip_runtime.h>
#include <hip/hip_bf16.h>
#include <math.h>

// B=8, N=1024, F=64, HEADS=8, u1=128, u2=64
#define NB 8
#define NN 1024
#define NH 8

typedef __attribute__((ext_vector_type(8))) short bf16x8;
typedef __attribute__((ext_vector_type(4))) float f32x4;
typedef unsigned int u32;
typedef unsigned short u16;

__device__ __forceinline__ u16 f2bf(float f) {
    union { float f; u32 u; } v; v.f = f;
    const u32 u = v.u;
    return (u16)((u + 0x7fffu + ((u >> 16) & 1u)) >> 16);
}

// ---------------------------------------------------------------------------
// Mask bit-pack: A [B,N,N] f32 (0/1) -> bits [B*N, 32] u32 (bit=1 => masked)
// One block per row, ballot per wave-iter.
// ---------------------------------------------------------------------------
__global__ __launch_bounds__(256) void mask_bits(const float* __restrict__ A,
                                                 u32* __restrict__ bits) {
    const int row = blockIdx.x;            // 0..B*N-1
    const int tid = threadIdx.x;
    const int lane = tid & 63;
    const float* __restrict__ ar = A + (size_t)row * NN;
#pragma unroll
    for (int it = 0; it < 4; ++it) {
        const int i = it * 256 + tid;
        const unsigned long long bal = __ballot(ar[i] != 0.0f);
        const int w0 = (it * 256 + (tid & ~63)) >> 5;
        if (lane == 0)  bits[(size_t)row * 32 + w0]     = (u32)bal;
        if (lane == 32) bits[(size_t)row * 32 + w0 + 1] = (u32)(bal >> 32);
    }
}

// ---------------------------------------------------------------------------
// Fused QKV projection -> bf16 outputs.
// X: [B*N, KIN] f32. W*: [KIN, HD] f32.
// Qb: [B,H,N,D] bf16 (pre-scaled by qscale), Kb: [B,H,N,D] bf16,
// VT: [B,H,D,N] bf16 (transposed for PV B-fragments).
// RB=16 rows/block, 256 threads; thread owns CPW contiguous cols, all rows.
// ---------------------------------------------------------------------------
template <int KIN, int HD, int D>
__global__ __launch_bounds__(256)
void proj_qkv_bf(const float* __restrict__ X,
                 const float* __restrict__ Wq,
                 const float* __restrict__ Wk,
                 const float* __restrict__ Wv,
                 u16* __restrict__ Qb,
                 u16* __restrict__ Kb,
                 u16* __restrict__ VT,
                 const float qscale) {
    constexpr int RB  = 16;
    constexpr int CPW = HD / 256;          // 4 (layer1) or 2 (layer2)
    const int r0  = blockIdx.x * RB;
    const int b   = r0 >> 10;
    const int n0  = r0 & 1023;
    const int tid = threadIdx.x;

    __shared__ float xs[RB][KIN];
    for (int i = tid; i < RB * KIN / 4; i += 256) {
        const int rr = i / (KIN / 4), ff = (i % (KIN / 4)) * 4;
        *(float4*)&xs[rr][ff] = *(const float4*)&X[(size_t)(r0 + rr) * KIN + ff];
    }
    __syncthreads();

    const int c0 = CPW * tid;
    const int h  = c0 / D;
    const int d0 = c0 % D;
    const int bh = b * NH + h;

    const float* Ws[3] = {Wq, Wk, Wv};
#pragma unroll 1
    for (int w = 0; w < 3; ++w) {
        const float* __restrict__ W = Ws[w];
        float acc[RB][CPW];
#pragma unroll
        for (int rr = 0; rr < RB; ++rr)
#pragma unroll
            for (int k = 0; k < CPW; ++k) acc[rr][k] = 0.f;

#pragma unroll 4
        for (int f = 0; f < KIN; ++f) {
            float wv[CPW];
            if constexpr (CPW == 4) {
                const float4 t = *(const float4*)&W[(size_t)f * HD + c0];
                wv[0] = t.x; wv[1] = t.y; wv[2] = t.z; wv[3] = t.w;
            } else {
                const float2 t = *(const float2*)&W[(size_t)f * HD + c0];
                wv[0] = t.x; wv[1] = t.y;
            }
#pragma unroll
            for (int rr = 0; rr < RB; ++rr) {
                const float xv = xs[rr][f];
#pragma unroll
                for (int k = 0; k < CPW; ++k) acc[rr][k] = fmaf(xv, wv[k], acc[rr][k]);
            }
        }

        if (w == 2) {
            // V transposed store: per col d, 16 contiguous n's
#pragma unroll
            for (int k = 0; k < CPW; ++k) {
                u32* dst = (u32*)&VT[((size_t)bh * D + d0 + k) * NN + n0];
                uint4 v0, v1;
                v0.x = (u32)f2bf(acc[0][k])  | ((u32)f2bf(acc[1][k])  << 16);
                v0.y = (u32)f2bf(acc[2][k])  | ((u32)f2bf(acc[3][k])  << 16);
                v0.z = (u32)f2bf(acc[4][k])  | ((u32)f2bf(acc[5][k])  << 16);
                v0.w = (u32)f2bf(acc[6][k])  | ((u32)f2bf(acc[7][k])  << 16);
                v1.x = (u32)f2bf(acc[8][k])  | ((u32)f2bf(acc[9][k])  << 16);
                v1.y = (u32)f2bf(acc[10][k]) | ((u32)f2bf(acc[11][k]) << 16);
                v1.z = (u32)f2bf(acc[12][k]) | ((u32)f2bf(acc[13][k]) << 16);
                v1.w = (u32)f2bf(acc[14][k]) | ((u32)f2bf(acc[15][k]) << 16);
                *(uint4*)dst       = v0;
                *(uint4*)(dst + 4) = v1;
            }
        } else {
            u16* __restrict__ O = (w == 0) ? Qb : Kb;
            const float sc = (w == 0) ? qscale : 1.0f;
#pragma unroll
            for (int rr = 0; rr < RB; ++rr) {
                u16* dst = &O[((size_t)bh * NN + (n0 + rr)) * D + d0];
                if constexpr (CPW == 4) {
                    uint2 v;
                    v.x = (u32)f2bf(acc[rr][0] * sc) | ((u32)f2bf(acc[rr][1] * sc) << 16);
                    v.y = (u32)f2bf(acc[rr][2] * sc) | ((u32)f2bf(acc[rr][3] * sc) << 16);
                    *(uint2*)dst = v;
                } else {
                    u32 v = (u32)f2bf(acc[rr][0] * sc) | ((u32)f2bf(acc[rr][1] * sc) << 16);
                    *(u32*)dst = v;
                }
            }
        }
    }
}

// ---------------------------------------------------------------------------
// MFMA flash attention. One WAVE per (bh, 32 q-rows); no block-level sync.
// Qb (pre-scaled by scale*log2e), Kb: [B,H,N,D] bf16; VT: [B,H,D,N] bf16.
// bits: [B*N, 32]. O: [B, N, H*D] f32.
// Per 32-key chunk: S = QK^T via mfma (C: col=lane&15=key, row=(lane>>4)*4+r=q),
// masked online softmax in log2 domain, P->LDS->A-frag, PV via mfma.
// ---------------------------------------------------------------------------
template <int D>
__global__ __launch_bounds__(256)
void attn_mfma(const u16* __restrict__ Qb,
               const u16* __restrict__ Kb,
               const u16* __restrict__ VT,
               const u32* __restrict__ bits,
               float* __restrict__ O) {
    constexpr int ND4 = D / 32;            // QK^T k-steps (4 / 2)
    constexpr int NDT = D / 16;            // PV d-tiles   (8 / 4)
    constexpr int PST = 40;                // P_lds row stride (bf16) - conflict pad

    const int tid  = threadIdx.x;
    const int w    = tid >> 6;
    const int lane = tid & 63;
    const int g    = lane >> 4;            // 0..3
    const int q16  = lane & 15;

    // XCD-bijective swizzle over 512 blocks: 8 XCDs x 64 contiguous
    const int swz = (blockIdx.x & 7) * 64 + (blockIdx.x >> 3);
    const int bh  = swz >> 3;              // 0..63 (8 bh per XCD)
    const int b   = bh >> 3;
    const int h   = bh & 7;
    const int qt  = (swz & 7) * 4 + w;     // 0..31
    const int q0  = qt * 32;

    const u16* __restrict__ qbase = Qb + (size_t)bh * NN * D;
    const u16* __restrict__ kbase = Kb + (size_t)bh * NN * D;
    const u16* __restrict__ vbase = VT + (size_t)bh * D * NN;

    __shared__ u16 Plds[4][2][16 * PST];

    // Q fragments (A-operand: row=lane&15, k=(lane>>4)*8+j)
    bf16x8 qf[2][ND4];
#pragma unroll
    for (int qs = 0; qs < 2; ++qs)
#pragma unroll
        for (int f = 0; f < ND4; ++f)
            qf[qs][f] = *(const bf16x8*)&qbase[((size_t)(q0 + qs * 16 + q16)) * D + f * 32 + g * 8];

    f32x4 acc[2][NDT];
    float m[2][4], l[2][4];
#pragma unroll
    for (int qs = 0; qs < 2; ++qs) {
#pragma unroll
        for (int dt = 0; dt < NDT; ++dt) acc[qs][dt] = (f32x4)0.f;
#pragma unroll
        for (int r = 0; r < 4; ++r) { m[qs][r] = -3.0e38f; l[qs][r] = 0.f; }
    }

    for (int ch = 0; ch < NN / 32; ++ch) {
        const int k0 = ch * 32;
        // mask words (broadcast across the 16-lane group)
        u32 bw[2][4];
#pragma unroll
        for (int qs = 0; qs < 2; ++qs)
#pragma unroll
            for (int r = 0; r < 4; ++r)
                bw[qs][r] = bits[((size_t)b * NN + q0 + qs * 16 + g * 4 + r) * 32 + ch];

        // K fragments (B-operand: col=lane&15=key, k=d)
        bf16x8 kf[2][ND4];
#pragma unroll
        for (int kb = 0; kb < 2; ++kb)
#pragma unroll
            for (int f = 0; f < ND4; ++f)
                kf[kb][f] = *(const bf16x8*)&kbase[((size_t)(k0 + kb * 16 + q16)) * D + f * 32 + g * 8];

#pragma unroll
        for (int qs = 0; qs < 2; ++qs) {
            f32x4 s[2];
            s[0] = (f32x4)0.f; s[1] = (f32x4)0.f;
#pragma unroll
            for (int kb = 0; kb < 2; ++kb)
#pragma unroll
                for (int f = 0; f < ND4; ++f)
                    s[kb] = __builtin_amdgcn_mfma_f32_16x16x32_bf16(qf[qs][f], kf[kb][f], s[kb], 0, 0, 0);

            // mask + per-row max (16-lane group reduce)
            float pmax[4];
#pragma unroll
            for (int r = 0; r < 4; ++r) {
                const u32 t = bw[qs][r] >> q16;
                float s0 = s[0][r] - ((t & 1u) ? 1.0e9f : 0.f);
                float s1 = s[1][r] - (((t >> 16) & 1u) ? 1.0e9f : 0.f);
                s[0][r] = s0; s[1][r] = s1;
                float mx = fmaxf(s0, s1);
#pragma unroll
                for (int off = 1; off < 16; off <<= 1)
                    mx = fmaxf(mx, __shfl_xor(mx, off, 16));
                pmax[r] = mx;
            }
            // defer-max rescale (wave-uniform branch)
            bool need = false;
#pragma unroll
            for (int r = 0; r < 4; ++r) need |= (pmax[r] > m[qs][r] + 8.f);
            if (__ballot(need) != 0ULL) {
#pragma unroll
                for (int r = 0; r < 4; ++r) {
                    const float mn = fmaxf(m[qs][r], pmax[r]);
                    const float al = exp2f(m[qs][r] - mn);
                    m[qs][r] = mn;
                    l[qs][r] *= al;
#pragma unroll
                    for (int dt = 0; dt < NDT; ++dt) acc[qs][dt][r] *= al;
                }
            }
            // P = exp2(s - m), accumulate l, store bf16 to LDS [q][k] (stride PST)
            u16* __restrict__ pl = &Plds[w][qs][0];
#pragma unroll
            for (int r = 0; r < 4; ++r) {
                const float p0 = exp2f(s[0][r] - m[qs][r]);
                const float p1 = exp2f(s[1][r] - m[qs][r]);
                l[qs][r] += p0 + p1;
                pl[(g * 4 + r) * PST + q16]      = f2bf(p0);
                pl[(g * 4 + r) * PST + 16 + q16] = f2bf(p1);
            }
        }

        // P A-fragments (within-wave LDS round-trip; compiler inserts lgkmcnt)
        bf16x8 pf[2];
#pragma unroll
        for (int qs = 0; qs < 2; ++qs)
            pf[qs] = *(const bf16x8*)&Plds[w][qs][q16 * PST + g * 8];

        // PV: V B-fragments from VT rows (col=lane&15=d, k=key)
#pragma unroll
        for (int dt = 0; dt < NDT; ++dt) {
            const bf16x8 vf = *(const bf16x8*)&vbase[((size_t)(dt * 16 + q16)) * NN + k0 + g * 8];
#pragma unroll
            for (int qs = 0; qs < 2; ++qs)
                acc[qs][dt] = __builtin_amdgcn_mfma_f32_16x16x32_bf16(pf[qs], vf, acc[qs][dt], 0, 0, 0);
        }
    }

    // epilogue: reduce l across 16-lane group, normalize, write O [B,N,H*D]
#pragma unroll
    for (int qs = 0; qs < 2; ++qs) {
        float inv[4];
#pragma unroll
        for (int r = 0; r < 4; ++r) {
            float ls = l[qs][r];
#pragma unroll
            for (int off = 1; off < 16; off <<= 1) ls += __shfl_xor(ls, off, 16);
            inv[r] = 1.0f / ls;
        }
#pragma unroll
        for (int dt = 0; dt < NDT; ++dt)
#pragma unroll
            for (int r = 0; r < 4; ++r) {
                const int q = q0 + qs * 16 + g * 4 + r;
                O[(((size_t)b * NN + q) * NH + h) * D + dt * 16 + q16] = acc[qs][dt][r] * inv[r];
            }
    }
}

// ---------------------------------------------------------------------------
// Row-tiled output projection (fp32). Hin: [rows, CIN], Wo: [CIN, COUT].
// ---------------------------------------------------------------------------
template <int CIN, int COUT, int RB>
__global__ __launch_bounds__(256)
void wo_proj_t(const float* __restrict__ Hin,
               const float* __restrict__ Wo,
               float* __restrict__ Hout) {
    constexpr int G   = 256 / COUT;
    constexpr int RPT = RB / G;
    const int r0  = blockIdx.x * RB;
    const int tid = threadIdx.x;

    __shared__ float xs[RB][CIN];
    for (int i = tid; i < RB * CIN / 4; i += 256) {
        const int rr = i / (CIN / 4), ff = (i % (CIN / 4)) * 4;
        *(float4*)&xs[rr][ff] = *(const float4*)&Hin[(size_t)(r0 + rr) * CIN + ff];
    }
    __syncthreads();

    const int c = tid % COUT;
    const int g = tid / COUT;
    float acc[RPT];
#pragma unroll
    for (int j = 0; j < RPT; ++j) acc[j] = 0.f;

#pragma unroll 4
    for (int f = 0; f < CIN; ++f) {
        const float wv = Wo[(size_t)f * COUT + c];
#pragma unroll
        for (int j = 0; j < RPT; ++j)
            acc[j] = fmaf(xs[g * RPT + j][f], wv, acc[j]);
    }
#pragma unroll
    for (int j = 0; j < RPT; ++j)
        Hout[(size_t)(r0 + g * RPT + j) * COUT + c] = acc[j];
}

// ---------------------------------------------------------------------------
// Mean over N + 3-layer MLP. One block per batch element.
// ---------------------------------------------------------------------------
__global__ void pool_mlp(const float* __restrict__ H2,
                         const float* __restrict__ W1, const float* __restrict__ b1,
                         const float* __restrict__ W2, const float* __restrict__ b2,
                         const float* __restrict__ W3, const float* __restrict__ b3,
                         float* __restrict__ out) {
    const int b = blockIdx.x;
    const int tid = threadIdx.x;       // 256
    __shared__ float red[4][64];
    __shared__ float mean[64];
    __shared__ float h1[32];
    __shared__ float h2[16];

    const int o = tid & 63;
    const int g = tid >> 6;
    float acc = 0.f;
    for (int n = g; n < NN; n += 4) acc += H2[((size_t)b * NN + n) * 64 + o];
    red[g][o] = acc;
    __syncthreads();
    if (g == 0) mean[o] = (red[0][o] + red[1][o] + red[2][o] + red[3][o]) * (1.0f / 1024.0f);
    __syncthreads();

    if (tid < 32) {
        float a = b1[tid];
#pragma unroll
        for (int f = 0; f < 64; ++f) a = fmaf(mean[f], W1[f * 32 + tid], a);
        h1[tid] = fmaxf(a, 0.f);
    }
    __syncthreads();
    if (tid < 16) {
        float a = b2[tid];
#pragma unroll
        for (int f = 0; f < 32; ++f) a = fmaf(h1[f], W2[f * 16 + tid], a);
        h2[tid] = fmaxf(a, 0.f);
    }
    __syncthreads();
    if (tid == 0) {
        float a = b3[0];
#pragma unroll
        for (int f = 0; f < 16; ++f) a = fmaf(h2[f], W3[f], a);
        out[b] = a;
    }
}

// ---------------------------------------------------------------------------
extern "C" void kernel_launch(void* const* d_in, const int* in_sizes, int n_in,
                              void* d_out, int out_size, void* d_ws, size_t ws_size,
                              hipStream_t stream) {
    const float* X   = (const float*)d_in[0];
    const float* A   = (const float*)d_in[1];
    const float* Wq1 = (const float*)d_in[2];
    const float* Wk1 = (const float*)d_in[3];
    const float* Wv1 = (const float*)d_in[4];
    const float* Wo1 = (const float*)d_in[5];
    const float* Wq2 = (const float*)d_in[6];
    const float* Wk2 = (const float*)d_in[7];
    const float* Wv2 = (const float*)d_in[8];
    const float* Wo2 = (const float*)d_in[9];
    const float* W1  = (const float*)d_in[10];
    const float* b1  = (const float*)d_in[11];
    const float* W2  = (const float*)d_in[12];
    const float* b2  = (const float*)d_in[13];
    const float* W3  = (const float*)d_in[14];
    const float* b3  = (const float*)d_in[15];
    float* out = (float*)d_out;

    // workspace layout
    u32* bits = (u32*)d_ws;                       // 262144 u32 = 1MB
    u16* Qb1  = (u16*)(bits + 262144);            // 8M bf16 = 16MB
    u16* Kb1  = Qb1 + 8388608;
    u16* VT1  = Kb1 + 8388608;
    float* ctx1 = (float*)(VT1 + 8388608);        // 8M f32 [B,N,1024]
    float* H1   = ctx1 + 8388608;                 // 1M f32 [B,N,128]
    u16* Qb2  = (u16*)(H1 + 1048576);             // 4M bf16
    u16* Kb2  = Qb2 + 4194304;
    u16* VT2  = Kb2 + 4194304;
    float* ctx2 = (float*)(VT2 + 4194304);        // 4M f32 [B,N,512]
    float* H2   = ctx2 + 4194304;                 // 0.5M f32 [B,N,64]

    const int ROWS = NB * NN;                     // 8192
    const float LOG2E = 1.4426950408889634f;

    mask_bits<<<ROWS, 256, 0, stream>>>(A, bits);

    // ----- layer 1 (D = 128) -----
    proj_qkv_bf<64, 1024, 128><<<ROWS / 16, 256, 0, stream>>>(
        X, Wq1, Wk1, Wv1, Qb1, Kb1, VT1, 0.08838834764831845f * LOG2E);
    attn_mfma<128><<<512, 256, 0, stream>>>(Qb1, Kb1, VT1, bits, ctx1);
    wo_proj_t<1024, 128, 8><<<ROWS / 8, 256, 0, stream>>>(ctx1, Wo1, H1);

    // ----- layer 2 (D = 64) -----
    proj_qkv_bf<128, 512, 64><<<ROWS / 16, 256, 0, stream>>>(
        H1, Wq2, Wk2, Wv2, Qb2, Kb2, VT2, 0.125f * LOG2E);
    attn_mfma<64><<<512, 256, 0, stream>>>(Qb2, Kb2, VT2, bits, ctx2);
    wo_proj_t<512, 64, 16><<<ROWS / 16, 256, 0, stream>>>(ctx2, Wo2, H2);

    // ----- pool + MLP -----
    pool_mlp<<<NB, 256, 0, stream>>>(H2, W1, b1, W2, b2, W3, b3, out);
}